// Round 14
// baseline (382.102 us; speedup 1.0000x reference)
//
#include <hip/hip_runtime.h>
#include <math.h>

#define S_LEN 2048
#define D_MODEL 1024
#define NH 16
#define DK 64
#define BATCH 4

// log2(10000)/64
#define ROPE_L2F 0.20762050593046014f
// 0.125 * log2(e): folds 1/sqrt(dk) and exp->exp2 conversion into Q
#define QSCALE 0.18033688011112042f

typedef __attribute__((ext_vector_type(8))) short bf16x8;
typedef __attribute__((ext_vector_type(4))) short short4v;
typedef __attribute__((ext_vector_type(2))) short short2v;
typedef __attribute__((ext_vector_type(4))) float f32x4;

__device__ inline short f2bf(float f) {            // RNE fp32 -> bf16 bits
    unsigned u = __builtin_bit_cast(unsigned, f);
    unsigned r = u + 0x7FFFu + ((u >> 16) & 1u);
    return (short)(r >> 16);
}

// packed fp32x2 -> bf16x2 (RNE), single VALU op
__device__ inline unsigned cvt_pk_bf16(float lo, float hi) {
    unsigned r;
    asm("v_cvt_pk_bf16_f32 %0, %1, %2" : "=v"(r) : "v"(lo), "v"(hi));
    return r;
}

// async global->LDS, 16B per lane; lds base must be wave-uniform.
__device__ inline void load_lds16(const void* g, void* l) {
    __builtin_amdgcn_global_load_lds(
        (const __attribute__((address_space(1))) unsigned int*)g,
        (__attribute__((address_space(3))) unsigned int*)l, 16, 0, 0);
}

// ---------------------------------------------------------------------------
// One-time fp32 -> bf16 conversions.
// ---------------------------------------------------------------------------
__global__ __launch_bounds__(256) void conv_bf16(
    const float* __restrict__ src, short* __restrict__ dst, int n)
{
    int i = (blockIdx.x * 256 + threadIdx.x) * 8;
    if (i >= n) return;
    float4 a = *(const float4*)&src[i];
    float4 b = *(const float4*)&src[i + 4];
    short h[8] = { f2bf(a.x), f2bf(a.y), f2bf(a.z), f2bf(a.w),
                   f2bf(b.x), f2bf(b.y), f2bf(b.z), f2bf(b.w) };
    *(bf16x8*)&dst[i] = *(bf16x8*)h;
}

__global__ __launch_bounds__(256) void conv_w4(
    const float* __restrict__ Wq, const float* __restrict__ Wk,
    const float* __restrict__ Wv, const float* __restrict__ Wo,
    short* __restrict__ dst)
{
    const float* srcs[4] = { Wq, Wk, Wv, Wo };
    const float* s = srcs[blockIdx.y];
    short* d = dst + (size_t)blockIdx.y * (D_MODEL * D_MODEL);
    int i = (blockIdx.x * 256 + threadIdx.x) * 8;
    float4 a = *(const float4*)&s[i];
    float4 b = *(const float4*)&s[i + 4];
    short h[8] = { f2bf(a.x), f2bf(a.y), f2bf(a.z), f2bf(a.w),
                   f2bf(b.x), f2bf(b.y), f2bf(b.z), f2bf(b.w) };
    *(bf16x8*)&d[i] = *(bf16x8*)h;
}

// ---------------------------------------------------------------------------
// RoPE cos/sin table: cst[si*32 + f] = (cos, sin) of tp[si] * theta^(-2f/64).
// ---------------------------------------------------------------------------
__global__ __launch_bounds__(256) void rope_tab(
    const int* __restrict__ tp, float2* __restrict__ cst)
{
    int idx = blockIdx.x * 256 + threadIdx.x;      // 65536 entries
    int si = idx >> 5;
    int f  = idx & 31;
    float pos = (float)tp[si];
    float freq = exp2f(-(float)(2 * f) * ROPE_L2F);
    float s, c;
    __sincosf(pos * freq, &s, &c);
    cst[idx] = make_float2(c, s);
}

// ---------------------------------------------------------------------------
// bf16 MFMA GEMM main loop (m97-style): 128x128 tile, 4 waves 2x2.
// 2-phase pipeline (round-12, neutral but kept): prologue stages buf 0;
// each BK=32 iter issues next chunk's loads into buf^1 FIRST, computes buf,
// then ONE __syncthreads (dbuf safe).
// SWAP=0: acc[mt][nt]=mfma(a_h,b_h) — M regs = token row, N lanes = feature.
// SWAP=1: acc[ft][tt]=mfma(b_h,a_h) — transposed (feature on regs) for the
// shuffle-free RoPE epilogue (round-11 win, ~22us).
// ---------------------------------------------------------------------------
#define PROJ_STAGE(BUF)                                                      \
    {                                                                        \
        load_lds16(agp, &As[BUF][wave * 32][0]);                             \
        load_lds16(agp + 16 * D_MODEL, &As[BUF][wave * 32 + 16][0]);         \
        load_lds16(bgp, &Bs[BUF][wave * 32][0]);                             \
        load_lds16(bgp + 16 * D_MODEL, &Bs[BUF][wave * 32 + 16][0]);         \
        agp += 32; bgp += 32;                                                \
    }

#define PROJ_PROLOGUE(SWAP)                                                  \
    __shared__ short As[2][128][32];                                         \
    __shared__ short Bs[2][128][32];                                         \
    const int m0 = blockIdx.y * 128;                                         \
    const int n0 = blockIdx.x * 128;                                         \
    const int tid = threadIdx.x;                                             \
    const int lane = tid & 63;                                               \
    const int wave = tid >> 6;                                               \
    const int quad = lane >> 4;                                              \
    const int l16 = lane & 15;                                               \
    const int wr = (wave >> 1) * 64;                                         \
    const int wc = (wave & 1) * 64;                                          \
    const int srow = wave * 32 + (lane >> 2);                                \
    const int schunk = (lane & 3) ^ ((lane >> 2) & 3);                       \
    const short* agp = &A[(size_t)(m0 + srow) * D_MODEL + schunk * 8];       \
    const short* bgp = &Bw[(size_t)(n0 + srow) * D_MODEL + schunk * 8];      \
    const int fchunk = quad ^ (l16 & 3);                                     \
    f32x4 acc[4][4] = {};                                                    \
    PROJ_STAGE(0)                                                            \
    __syncthreads();                                                         \
    _Pragma("unroll 2")                                                      \
    for (int k0 = 0; k0 < D_MODEL; k0 += 32) {                               \
        const int cur = (k0 >> 5) & 1;                                       \
        if (k0 + 32 < D_MODEL) PROJ_STAGE(cur ^ 1)                           \
        bf16x8 a_h[4], b_h[4];                                               \
        _Pragma("unroll")                                                    \
        for (int t = 0; t < 4; ++t) {                                        \
            a_h[t] = *(const bf16x8*)                                        \
                &As[cur][wr + t * 16 + l16][fchunk * 8];                     \
            b_h[t] = *(const bf16x8*)                                        \
                &Bs[cur][wc + t * 16 + l16][fchunk * 8];                     \
        }                                                                    \
        _Pragma("unroll")                                                    \
        for (int i = 0; i < 4; ++i)                                          \
            _Pragma("unroll")                                                \
            for (int j = 0; j < 4; ++j)                                      \
                acc[i][j] = __builtin_amdgcn_mfma_f32_16x16x32_bf16(         \
                    (SWAP) ? b_h[i] : a_h[i],                                \
                    (SWAP) ? a_h[j] : b_h[j],                                \
                    acc[i][j], 0, 0, 0);                                     \
        __syncthreads();                                                     \
    }

// ---------------------------------------------------------------------------
// Fused QKV projection: C = x (8192x1024) @ [Wq;Wk;Wv]^T (1024x3072).
// TRANSPOSED epilogue (SWAP=1): acc[ft][tt]; per lane, M-reg dim = 4
// consecutive FEATURES (quad*4+r), lane dim = TOKEN (l16). RoPE even/odd
// pairs are (reg0,reg1),(reg2,reg3) — no shuffles; cvt_pk packs; one
// uint2 (8B) store per (ft,tt) instead of 4 scalar 2B stores.
// ---------------------------------------------------------------------------
__global__ __launch_bounds__(256) void proj_qkv(
    const short* __restrict__ A, const short* __restrict__ Bw,
    const float2* __restrict__ cst,
    short* __restrict__ Qo, short* __restrict__ Ko, short* __restrict__ Vo)
{
    PROJ_PROLOGUE(1)

    const int which = n0 >> 10;                    // 0=Q 1=K 2=V
    short* __restrict__ outp = (which == 0) ? Qo : (which == 1) ? Ko : Vo;
    const float scale = (which == 0) ? QSCALE : 1.0f;
    const int nbase = n0 & (D_MODEL - 1);

#pragma unroll
    for (int ft = 0; ft < 4; ++ft) {
        const int colb = nbase + wc + ft * 16 + quad * 4;  // feature, 4-aligned
        const int head = colb >> 6;
        const int tloc = colb & 63;
#pragma unroll
        for (int tt = 0; tt < 4; ++tt) {
            const int row = m0 + wr + tt * 16 + l16;       // token
            const int bi = row >> 11;
            const int si = row & (S_LEN - 1);
            f32x4 v = acc[ft][tt];
            uint2 uu;
            if (which < 2) {
                float2 cs0 = cst[si * 32 + (tloc >> 1)];
                float2 cs1 = cst[si * 32 + (tloc >> 1) + 1];
                uu.x = cvt_pk_bf16((cs0.x * v[0] - cs0.y * v[1]) * scale,
                                   (cs0.y * v[0] + cs0.x * v[1]) * scale);
                uu.y = cvt_pk_bf16((cs1.x * v[2] - cs1.y * v[3]) * scale,
                                   (cs1.y * v[2] + cs1.x * v[3]) * scale);
            } else {
                uu.x = cvt_pk_bf16(v[0], v[1]);
                uu.y = cvt_pk_bf16(v[2], v[3]);
            }
            *(uint2*)&outp[(((size_t)bi * NH + head) * S_LEN + si) * DK +
                           tloc] = uu;
        }
    }
}

// ---------------------------------------------------------------------------
// Output projection: out = attnO (8192x1024) @ Wo^T, fp32 row-major.
// ---------------------------------------------------------------------------
__global__ __launch_bounds__(256) void proj_out(
    const short* __restrict__ A, const short* __restrict__ Bw,
    float* __restrict__ outf)
{
    PROJ_PROLOGUE(0)

#pragma unroll
    for (int mt = 0; mt < 4; ++mt) {
#pragma unroll
        for (int r = 0; r < 4; ++r) {
            const int row = m0 + wr + mt * 16 + quad * 4 + r;
#pragma unroll
            for (int nt = 0; nt < 4; ++nt) {
                int col = n0 + wc + nt * 16 + l16;
                outf[(size_t)row * D_MODEL + col] = acc[mt][nt][r];
            }
        }
    }
}

// ---------------------------------------------------------------------------
// MFMA flash causal attention — ROUND 14: MERGED HALVES.
// Lesson ledger: occupancy up (r5/r9) ✗; live-state interleave (r13) ✗;
// fixed-cost amortization (r4) ✓. This round amortizes harder: the two
// q-tiles per block (bx0=15-pair, bx1=pair; bx1 < bx0 so half1's K-range is
// a strict PREFIX of half0's) now share ONE k-loop. Each K tile is loaded
// into regs once and each V tile staged once FOR BOTH halves; iteration
// count 34 -> 32-2*pair (mean 25, -26% barriers/K-loads/V-commits).
// Per-wave state stays FAT (r5/r9 lesson): second accumulator set added,
// Kf double-buffer dropped to pay for it (~240 VGPR est, still <=256 =>
// 2 waves/SIMD). No manual interleave (r13 lesson): halves run
// sequentially per tile; their chains are independent so the scheduler
// overlaps PV(h0) MFMA with QK(h1) for free. Ps/Vt reused sequentially
// (wave-private; lgkmcnt orders the WAR on Ps).
// Kept: XCD head-grouping, lane-local defer-max (THR=8), lane-partial l,
// cvt_pk P-packing, one barrier per 2 tiles (Vt 4-deep).
// ---------------------------------------------------------------------------
#define PADS 72

#define ATTN_TILE(S)                                                         \
    {                                                                        \
        f32x4 sT2[2][4];                                                     \
        _Pragma("unroll")                                                    \
        for (int sub = 0; sub < 2; ++sub) {                                  \
            _Pragma("unroll")                                                \
            for (int kt = 0; kt < 4; ++kt) sT2[sub][kt] = f32x4{};           \
            _Pragma("unroll")                                                \
            for (int c = 0; c < 2; ++c)                                      \
                _Pragma("unroll")                                            \
                for (int kt = 0; kt < 4; ++kt)                               \
                    sT2[sub][kt] = __builtin_amdgcn_mfma_f32_16x16x32_bf16(  \
                        Kf[kt][c], Qf##S[sub][c], sT2[sub][kt], 0, 0, 0);    \
        }                                                                    \
        _Pragma("unroll")                                                    \
        for (int sub = 0; sub < 2; ++sub) {                                  \
            f32x4* sT = sT2[sub];                                            \
            const int qg = qbase##S + sub * 16 + l16;                        \
            if (k0 + 63 > qbase##S + sub * 16) {                             \
                _Pragma("unroll")                                            \
                for (int kt = 0; kt < 4; ++kt)                               \
                    _Pragma("unroll")                                        \
                    for (int r = 0; r < 4; ++r)                              \
                        if (k0 + kt * 16 + quad * 4 + r > qg)                \
                            sT[kt][r] = -1e30f;                              \
            }                                                                \
            float tmax = fmaxf(                                              \
                fmaxf(fmaxf(sT[0][0], sT[0][1]), fmaxf(sT[0][2], sT[0][3])), \
                fmaxf(fmaxf(fmaxf(sT[1][0], sT[1][1]),                       \
                            fmaxf(sT[1][2], sT[1][3])),                      \
                      fmaxf(fmaxf(fmaxf(sT[2][0], sT[2][1]),                 \
                                  fmaxf(sT[2][2], sT[2][3])),                \
                            fmaxf(fmaxf(sT[3][0], sT[3][1]),                 \
                                  fmaxf(sT[3][2], sT[3][3])))));             \
            if (!__all(tmax <= mi##S[sub] + 8.0f)) {                         \
                float tm = fmaxf(tmax, __shfl_xor(tmax, 16));                \
                tm = fmaxf(tm, __shfl_xor(tm, 32));                          \
                float mnew = fmaxf(mi##S[sub], tm);                          \
                float alpha = exp2f(mi##S[sub] - mnew);                      \
                mi##S[sub] = mnew;                                           \
                li##S[sub] *= alpha;                                         \
                _Pragma("unroll")                                            \
                for (int dt = 0; dt < 4; ++dt) {                             \
                    o##S[sub][dt][0] *= alpha; o##S[sub][dt][1] *= alpha;    \
                    o##S[sub][dt][2] *= alpha; o##S[sub][dt][3] *= alpha;    \
                }                                                            \
            }                                                                \
            const float mn = mi##S[sub];                                     \
            float rs = 0.0f;                                                 \
            const int prow = wave * 32 + sub * 16 + l16;                     \
            _Pragma("unroll")                                                \
            for (int kt = 0; kt < 4; ++kt) {                                 \
                float p0 = exp2f(sT[kt][0] - mn);                            \
                float p1 = exp2f(sT[kt][1] - mn);                            \
                float p2 = exp2f(sT[kt][2] - mn);                            \
                float p3 = exp2f(sT[kt][3] - mn);                            \
                rs += (p0 + p1) + (p2 + p3);                                 \
                uint2 uu;                                                    \
                uu.x = cvt_pk_bf16(p0, p1);                                  \
                uu.y = cvt_pk_bf16(p2, p3);                                  \
                *(uint2*)&Ps[prow][kt * 16 + quad * 4] = uu;                 \
            }                                                                \
            li##S[sub] += rs;                                                \
        }                                                                    \
        bf16x8 Pf[2][2];                                                     \
        _Pragma("unroll")                                                    \
        for (int sub = 0; sub < 2; ++sub)                                    \
            _Pragma("unroll")                                                \
            for (int c = 0; c < 2; ++c)                                      \
                Pf[sub][c] = *(const bf16x8*)                                \
                    &Ps[wave * 32 + sub * 16 + l16][c * 32 + quad * 8];      \
        _Pragma("unroll")                                                    \
        for (int c = 0; c < 2; ++c)                                          \
            _Pragma("unroll")                                                \
            for (int dt = 0; dt < 4; ++dt) {                                 \
                bf16x8 av = *(const bf16x8*)                                 \
                    &Vt[buf][dt * 16 + l16][c * 32 + quad * 8];              \
                _Pragma("unroll")                                            \
                for (int sub = 0; sub < 2; ++sub)                            \
                    o##S[sub][dt] = __builtin_amdgcn_mfma_f32_16x16x32_bf16( \
                        av, Pf[sub][c], o##S[sub][dt], 0, 0, 0);             \
            }                                                                \
    }

#define ATTN_EPI(S)                                                          \
    _Pragma("unroll")                                                        \
    for (int sub = 0; sub < 2; ++sub) {                                      \
        float lt = li##S[sub];                                               \
        lt += __shfl_xor(lt, 16);                                            \
        lt += __shfl_xor(lt, 32);                                            \
        const float linv = 1.0f / lt;                                        \
        const int q = qbase##S + sub * 16 + l16;                             \
        short* ob = &O[((size_t)bi * S_LEN + q) * D_MODEL + head * DK];      \
        _Pragma("unroll")                                                    \
        for (int dt = 0; dt < 4; ++dt) {                                     \
            short4v h;                                                       \
            h.x = f2bf(o##S[sub][dt][0] * linv);                             \
            h.y = f2bf(o##S[sub][dt][1] * linv);                             \
            h.z = f2bf(o##S[sub][dt][2] * linv);                             \
            h.w = f2bf(o##S[sub][dt][3] * linv);                             \
            *(short4v*)&ob[dt * 16 + quad * 4] = h;                          \
        }                                                                    \
    }

__global__ __launch_bounds__(256) void attn_bf16(
    const short* __restrict__ Q, const short* __restrict__ K,
    const short* __restrict__ V, short* __restrict__ O)
{
    __shared__ short Vt[4][64][PADS];  // V tiles transposed [d][k], 2 dbuf pairs
    __shared__ short Ps[128][PADS];    // P rows, wave-private (halves sequential)

    const int bh   = blockIdx.x * 8 + (blockIdx.y >> 3);
    const int pair = blockIdx.y & 7;

    const int tid = threadIdx.x;
    const int wave = tid >> 6;
    const int lane = tid & 63;
    const int quad = lane >> 4;
    const int l16 = lane & 15;

    const short* Kb = K + (size_t)bh * S_LEN * DK;
    const short* Vb = V + (size_t)bh * S_LEN * DK;

    // V staging geometry (transpose via short2)
    const int kp2 = (tid & 31) * 2;
    const int db = (tid >> 5) * 8;

    const int bi = bh >> 4;
    const int head = bh & 15;

    const int bx0 = 15 - pair;                     // heavy q-tile
    const int bx1 = pair;                          // light q-tile (prefix K-range)
    const int qbase0 = bx0 * 128 + wave * 32;
    const int qbase1 = bx1 * 128 + wave * 32;
    const int qlim0 = qbase0 + 31;
    const int qlim1 = qbase1 + 31;

    // Q fragments for BOTH halves (wave-private rows)
    bf16x8 Qf0[2][2], Qf1[2][2];
#pragma unroll
    for (int sub = 0; sub < 2; ++sub)
#pragma unroll
        for (int c = 0; c < 2; ++c) {
            Qf0[sub][c] = *(const bf16x8*)
                &Q[((size_t)bh * S_LEN + qbase0 + sub * 16 + l16) * DK +
                   c * 32 + quad * 8];
            Qf1[sub][c] = *(const bf16x8*)
                &Q[((size_t)bh * S_LEN + qbase1 + sub * 16 + l16) * DK +
                   c * 32 + quad * 8];
        }

    // preload V tiles 0,1 into regs
    bf16x8 va0 = *(const bf16x8*)&Vb[(size_t)kp2 * DK + db];
    bf16x8 va1 = *(const bf16x8*)&Vb[(size_t)(kp2 + 1) * DK + db];
    bf16x8 vb0 = *(const bf16x8*)&Vb[(size_t)(64 + kp2) * DK + db];
    bf16x8 vb1 = *(const bf16x8*)&Vb[(size_t)(64 + kp2 + 1) * DK + db];

    float mi0[2] = { -1e30f, -1e30f }, li0[2] = { 0.0f, 0.0f };
    float mi1[2] = { -1e30f, -1e30f }, li1[2] = { 0.0f, 0.0f };
    f32x4 o0[2][4] = {}, o1[2][4] = {};

    const int ktiles = 2 * bx0 + 2;                // covers both halves
    for (int tt = 0; tt < ktiles; tt += 2) {
        const int bufA = (tt & 2);

        // ---- commit both prefetched V tiles ----
#pragma unroll
        for (int i = 0; i < 8; ++i) {
            short2v pa; pa.x = va0[i]; pa.y = va1[i];
            *(short2v*)&Vt[bufA][db + i][kp2] = pa;
            short2v pb; pb.x = vb0[i]; pb.y = vb1[i];
            *(short2v*)&Vt[bufA | 1][db + i][kp2] = pb;
        }
        __syncthreads();               // one barrier per 2 tiles

        // ---- prefetch V tiles tt+2, tt+3 ----
        if (tt + 2 < ktiles) {
            const short* vp = &Vb[(size_t)((tt + 2) * 64 + kp2) * DK + db];
            va0 = *(const bf16x8*)vp;
            va1 = *(const bf16x8*)(vp + DK);
            vp += (size_t)64 * DK;
            vb0 = *(const bf16x8*)vp;
            vb1 = *(const bf16x8*)(vp + DK);
        }

#pragma unroll
        for (int sel = 0; sel < 2; ++sel) {
            const int t  = tt + sel;
            const int k0 = t * 64;
            const int buf = bufA | sel;
            if (k0 > qlim0) continue;  // qlim1 < qlim0, so both dead

            // K frags ONCE per tile, shared by both halves
            bf16x8 Kf[4][2];
#pragma unroll
            for (int kt = 0; kt < 4; ++kt)
#pragma unroll
                for (int c = 0; c < 2; ++c)
                    Kf[kt][c] = *(const bf16x8*)
                        &Kb[(size_t)(k0 + kt * 16 + l16) * DK +
                            c * 32 + quad * 8];

            ATTN_TILE(0)                           // heavy half: always live
            if (k0 <= qlim1) ATTN_TILE(1)          // light half: prefix tiles
        }
    }

    // ---- epilogue: both halves ----
    ATTN_EPI(0)
    ATTN_EPI(1)
}

extern "C" void kernel_launch(void* const* d_in, const int* in_sizes, int n_in,
                              void* d_out, int out_size, void* d_ws, size_t ws_size,
                              hipStream_t stream) {
    const float* x  = (const float*)d_in[0];
    const float* Wq = (const float*)d_in[1];
    const float* Wk = (const float*)d_in[2];
    const float* Wv = (const float*)d_in[3];
    const float* Wo = (const float*)d_in[4];
    const int*   tp = (const int*)d_in[5];
    float* out = (float*)d_out;

    const int n  = BATCH * S_LEN * D_MODEL;       // 8388608
    const int nw = D_MODEL * D_MODEL;             // 1048576
    short* sw   = (short*)d_ws;
    short* xbf  = sw;
    short* Qbf  = sw + (size_t)n;
    short* Kbf  = sw + (size_t)2 * n;
    short* Vbf  = sw + (size_t)3 * n;
    short* Obf  = sw + (size_t)4 * n;
    short* Wqbf = sw + (size_t)5 * n;             // Wq;Wk;Wv contiguous (3072x1024)
    short* Wobf = Wqbf + (size_t)3 * nw;
    // RoPE table overlaid on Obf (dead until attn writes it; stream order
    // guarantees rope_tab -> proj_qkv(read) -> attn(overwrite) -> proj_out).
    float2* cst = (float2*)Obf;                   // 512 KB of the 16.8 MB region

    dim3 blk(256);
    conv_bf16<<<n / (256 * 8), blk, 0, stream>>>(x, xbf, n);
    dim3 gw(nw / (256 * 8), 4);
    conv_w4<<<gw, blk, 0, stream>>>(Wq, Wk, Wv, Wo, Wqbf);
    rope_tab<<<(S_LEN * 32) / 256, blk, 0, stream>>>(tp, cst);

    dim3 gqkv(3 * D_MODEL / 128, (BATCH * S_LEN) / 128);   // (24, 64)
    proj_qkv<<<gqkv, blk, 0, stream>>>(xbf, Wqbf, cst, Qbf, Kbf, Vbf);

    dim3 gattn(8, BATCH * NH);                             // merged halves
    attn_bf16<<<gattn, blk, 0, stream>>>(Qbf, Kbf, Vbf, Obf);

    dim3 gout(D_MODEL / 128, (BATCH * S_LEN) / 128);       // (8, 64)
    proj_out<<<gout, blk, 0, stream>>>(Obf, Wobf, out);
}

// Round 15
// 344.037 us; speedup vs baseline: 1.1106x; 1.1106x over previous
//
#include <hip/hip_runtime.h>
#include <math.h>

#define S_LEN 2048
#define D_MODEL 1024
#define NH 16
#define DK 64
#define BATCH 4

// log2(10000)/64
#define ROPE_L2F 0.20762050593046014f
// 0.125 * log2(e): folds 1/sqrt(dk) and exp->exp2 conversion into Q
#define QSCALE 0.18033688011112042f

typedef __attribute__((ext_vector_type(8))) short bf16x8;
typedef __attribute__((ext_vector_type(4))) short short4v;
typedef __attribute__((ext_vector_type(2))) short short2v;
typedef __attribute__((ext_vector_type(4))) float f32x4;

__device__ inline short f2bf(float f) {            // RNE fp32 -> bf16 bits
    unsigned u = __builtin_bit_cast(unsigned, f);
    unsigned r = u + 0x7FFFu + ((u >> 16) & 1u);
    return (short)(r >> 16);
}

// packed fp32x2 -> bf16x2 (RNE), single VALU op
__device__ inline unsigned cvt_pk_bf16(float lo, float hi) {
    unsigned r;
    asm("v_cvt_pk_bf16_f32 %0, %1, %2" : "=v"(r) : "v"(lo), "v"(hi));
    return r;
}

// async global->LDS, 16B per lane; lds base must be wave-uniform.
__device__ inline void load_lds16(const void* g, void* l) {
    __builtin_amdgcn_global_load_lds(
        (const __attribute__((address_space(1))) unsigned int*)g,
        (__attribute__((address_space(3))) unsigned int*)l, 16, 0, 0);
}

// ---------------------------------------------------------------------------
// One-time fp32 -> bf16 conversions.
// ---------------------------------------------------------------------------
__global__ __launch_bounds__(256) void conv_bf16(
    const float* __restrict__ src, short* __restrict__ dst, int n)
{
    int i = (blockIdx.x * 256 + threadIdx.x) * 8;
    if (i >= n) return;
    float4 a = *(const float4*)&src[i];
    float4 b = *(const float4*)&src[i + 4];
    short h[8] = { f2bf(a.x), f2bf(a.y), f2bf(a.z), f2bf(a.w),
                   f2bf(b.x), f2bf(b.y), f2bf(b.z), f2bf(b.w) };
    *(bf16x8*)&dst[i] = *(bf16x8*)h;
}

__global__ __launch_bounds__(256) void conv_w4(
    const float* __restrict__ Wq, const float* __restrict__ Wk,
    const float* __restrict__ Wv, const float* __restrict__ Wo,
    short* __restrict__ dst)
{
    const float* srcs[4] = { Wq, Wk, Wv, Wo };
    const float* s = srcs[blockIdx.y];
    short* d = dst + (size_t)blockIdx.y * (D_MODEL * D_MODEL);
    int i = (blockIdx.x * 256 + threadIdx.x) * 8;
    float4 a = *(const float4*)&s[i];
    float4 b = *(const float4*)&s[i + 4];
    short h[8] = { f2bf(a.x), f2bf(a.y), f2bf(a.z), f2bf(a.w),
                   f2bf(b.x), f2bf(b.y), f2bf(b.z), f2bf(b.w) };
    *(bf16x8*)&d[i] = *(bf16x8*)h;
}

// ---------------------------------------------------------------------------
// RoPE cos/sin table: cst[si*32 + f] = (cos, sin) of tp[si] * theta^(-2f/64).
// ---------------------------------------------------------------------------
__global__ __launch_bounds__(256) void rope_tab(
    const int* __restrict__ tp, float2* __restrict__ cst)
{
    int idx = blockIdx.x * 256 + threadIdx.x;      // 65536 entries
    int si = idx >> 5;
    int f  = idx & 31;
    float pos = (float)tp[si];
    float freq = exp2f(-(float)(2 * f) * ROPE_L2F);
    float s, c;
    __sincosf(pos * freq, &s, &c);
    cst[idx] = make_float2(c, s);
}

// ---------------------------------------------------------------------------
// bf16 MFMA GEMM core (m97-style): 128x128 tile, 4 waves 2x2, BK=32,
// 2-phase pipeline (stage next buf, compute cur, one barrier). Assumes
// As/Bs declared by caller ([2][128][32] layout). SWAP as in round 11/12.
// ---------------------------------------------------------------------------
#define PROJ_STAGE(BUF)                                                      \
    {                                                                        \
        load_lds16(agp, &As[BUF][wave * 32][0]);                             \
        load_lds16(agp + 16 * D_MODEL, &As[BUF][wave * 32 + 16][0]);         \
        load_lds16(bgp, &Bs[BUF][wave * 32][0]);                             \
        load_lds16(bgp + 16 * D_MODEL, &Bs[BUF][wave * 32 + 16][0]);         \
        agp += 32; bgp += 32;                                                \
    }

#define PROJ_CORE(SWAP)                                                      \
    const int m0 = blockIdx.y * 128;                                         \
    const int n0 = blockIdx.x * 128;                                         \
    const int tid = threadIdx.x;                                             \
    const int lane = tid & 63;                                               \
    const int wave = tid >> 6;                                               \
    const int quad = lane >> 4;                                              \
    const int l16 = lane & 15;                                               \
    const int wr = (wave >> 1) * 64;                                         \
    const int wc = (wave & 1) * 64;                                          \
    const int srow = wave * 32 + (lane >> 2);                                \
    const int schunk = (lane & 3) ^ ((lane >> 2) & 3);                       \
    const short* agp = &A[(size_t)(m0 + srow) * D_MODEL + schunk * 8];       \
    const short* bgp = &Bw[(size_t)(n0 + srow) * D_MODEL + schunk * 8];      \
    const int fchunk = quad ^ (l16 & 3);                                     \
    f32x4 acc[4][4] = {};                                                    \
    PROJ_STAGE(0)                                                            \
    __syncthreads();                                                         \
    _Pragma("unroll 2")                                                      \
    for (int k0 = 0; k0 < D_MODEL; k0 += 32) {                               \
        const int cur = (k0 >> 5) & 1;                                       \
        if (k0 + 32 < D_MODEL) PROJ_STAGE(cur ^ 1)                           \
        bf16x8 a_h[4], b_h[4];                                               \
        _Pragma("unroll")                                                    \
        for (int t = 0; t < 4; ++t) {                                        \
            a_h[t] = *(const bf16x8*)                                        \
                &As[cur][wr + t * 16 + l16][fchunk * 8];                     \
            b_h[t] = *(const bf16x8*)                                        \
                &Bs[cur][wc + t * 16 + l16][fchunk * 8];                     \
        }                                                                    \
        _Pragma("unroll")                                                    \
        for (int i = 0; i < 4; ++i)                                          \
            _Pragma("unroll")                                                \
            for (int j = 0; j < 4; ++j)                                      \
                acc[i][j] = __builtin_amdgcn_mfma_f32_16x16x32_bf16(         \
                    (SWAP) ? b_h[i] : a_h[i],                                \
                    (SWAP) ? a_h[j] : b_h[j],                                \
                    acc[i][j], 0, 0, 0);                                     \
        __syncthreads();                                                     \
    }

// ---------------------------------------------------------------------------
// Fused QKV projection: C = x (8192x1024) @ [Wq;Wk;Wv]^T (1024x3072).
// Transposed MFMA (SWAP=1): acc[ft][tt], feature on regs (quad*4+r), token
// on lanes (l16) — shuffle-free RoPE (round-11 win).
// ROUND 15: LDS-STAGED COALESCED STORES. Old epilogue: 16 x 8B stores at
// 128B stride (16 lines touched per inst — scattered). New: RoPE'd bf16 ->
// Ct[128][130] in LDS (aliases As/Bs, dead after k-loop's final barrier;
// pad 130 => ~2-way banks) -> barrier -> 8 passes of fully-coalesced
// 16B/lane stores (32 head-rows x 128B = 4KB per pass).
// ---------------------------------------------------------------------------
__global__ __launch_bounds__(256) void proj_qkv(
    const short* __restrict__ A, const short* __restrict__ Bw,
    const float2* __restrict__ cst,
    short* __restrict__ Qo, short* __restrict__ Ko, short* __restrict__ Vo)
{
    __shared__ char smem[33792];
    short (*As)[128][32] = (short (*)[128][32])smem;
    short (*Bs)[128][32] = (short (*)[128][32])(smem + 16384);

    PROJ_CORE(1)

    const int which = n0 >> 10;                    // 0=Q 1=K 2=V
    short* __restrict__ outp = (which == 0) ? Qo : (which == 1) ? Ko : Vo;
    const float scale = (which == 0) ? QSCALE : 1.0f;
    const int nbase = n0 & (D_MODEL - 1);

    // ---- RoPE + pack into LDS C-tile (token-major, block-local) ----
    short (*Ct)[130] = (short (*)[130])smem;       // 128x130 shorts = 33.3KB
    const int si0 = m0 & (S_LEN - 1);
#pragma unroll
    for (int ft = 0; ft < 4; ++ft) {
        const int feat_loc = wc + ft * 16 + quad * 4;      // 0..127, 4-aligned
        const int tloc = feat_loc & 63;                    // nbase % 64 == 0
#pragma unroll
        for (int tt = 0; tt < 4; ++tt) {
            const int token_loc = wr + tt * 16 + l16;      // 0..127
            const int si = si0 + token_loc;
            f32x4 v = acc[ft][tt];
            uint2 uu;
            if (which < 2) {
                float2 cs0 = cst[si * 32 + (tloc >> 1)];
                float2 cs1 = cst[si * 32 + (tloc >> 1) + 1];
                uu.x = cvt_pk_bf16((cs0.x * v[0] - cs0.y * v[1]) * scale,
                                   (cs0.y * v[0] + cs0.x * v[1]) * scale);
                uu.y = cvt_pk_bf16((cs1.x * v[2] - cs1.y * v[3]) * scale,
                                   (cs1.y * v[2] + cs1.x * v[3]) * scale);
            } else {
                uu.x = cvt_pk_bf16(v[0], v[1]);
                uu.y = cvt_pk_bf16(v[2], v[3]);
            }
            *(uint2*)&Ct[token_loc][feat_loc] = uu;
        }
    }
    __syncthreads();

    // ---- coalesced store: 256 rows (128 tokens x 2 heads) x 128B ----
    const int bi = m0 >> 11;                       // uniform (128 | 2048)
    const int head0 = nbase >> 6;
    const int chunk = tid & 7;                     // 16B chunk within row
    const int rbase = tid >> 3;                    // 0..31
#pragma unroll
    for (int p = 0; p < 8; ++p) {
        const int row = p * 32 + rbase;            // 0..255
        const int hsel = row >> 7;
        const int tokl = row & 127;
        bf16x8 v = *(const bf16x8*)&Ct[tokl][hsel * 64 + chunk * 8];
        *(bf16x8*)&outp[(((size_t)bi * NH + head0 + hsel) * S_LEN +
                         si0 + tokl) * DK + chunk * 8] = v;
    }
}

// ---------------------------------------------------------------------------
// Output projection: out = attnO (8192x1024) @ Wo^T, fp32 row-major.
// Standard orientation (SWAP=0): stores already coalesced.
// ---------------------------------------------------------------------------
__global__ __launch_bounds__(256) void proj_out(
    const short* __restrict__ A, const short* __restrict__ Bw,
    float* __restrict__ outf)
{
    __shared__ short AsArr[2][128][32];
    __shared__ short BsArr[2][128][32];
    short (*As)[128][32] = AsArr;
    short (*Bs)[128][32] = BsArr;

    PROJ_CORE(0)

#pragma unroll
    for (int mt = 0; mt < 4; ++mt) {
#pragma unroll
        for (int r = 0; r < 4; ++r) {
            const int row = m0 + wr + mt * 16 + quad * 4 + r;
#pragma unroll
            for (int nt = 0; nt < 4; ++nt) {
                int col = n0 + wc + nt * 16 + l16;
                outf[(size_t)row * D_MODEL + col] = acc[mt][nt][r];
            }
        }
    }
}

// ---------------------------------------------------------------------------
// MFMA flash causal attention — ROUND-6 VERSION (verified ~154us, 3 times).
// Falsified alternatives ledger: r5/r9 thin-wave occupancy (remat chain),
// r13 two-tile live-state interleave (+VGPR, no gain), r14 merged halves
// (broke uniform-work invariant + exposed K latency). 2 fat waves/SIMD,
// reg-dbuf'd K, uniform 34 tiles/block is the local optimum.
// ---------------------------------------------------------------------------
#define PADS 72

__global__ __launch_bounds__(256) void attn_bf16(
    const short* __restrict__ Q, const short* __restrict__ K,
    const short* __restrict__ V, short* __restrict__ O)
{
    __shared__ short Vt[4][64][PADS];  // V tiles transposed [d][k], 2 dbuf pairs
    __shared__ short Ps[128][PADS];    // P rows, wave-private

    const int bh   = blockIdx.x * 8 + (blockIdx.y >> 3);
    const int pair = blockIdx.y & 7;

    const int tid = threadIdx.x;
    const int wave = tid >> 6;
    const int lane = tid & 63;
    const int quad = lane >> 4;
    const int l16 = lane & 15;

    const short* Kb = K + (size_t)bh * S_LEN * DK;
    const short* Vb = V + (size_t)bh * S_LEN * DK;

    // V staging geometry (transpose via short2)
    const int kp2 = (tid & 31) * 2;
    const int db = (tid >> 5) * 8;

    const int bi = bh >> 4;
    const int head = bh & 15;

    for (int half = 0; half < 2; ++half) {
        const int bx = half ? pair : (15 - pair);
        const int qbase = bx * 128 + wave * 32;
        const int qlim = qbase + 31;

        // Q fragments straight from global (wave-private rows)
        bf16x8 Qf[2][2];
#pragma unroll
        for (int sub = 0; sub < 2; ++sub)
#pragma unroll
            for (int c = 0; c < 2; ++c)
                Qf[sub][c] = *(const bf16x8*)
                    &Q[((size_t)bh * S_LEN + qbase + sub * 16 + l16) * DK +
                       c * 32 + quad * 8];

        // preload tiles 0,1: V rows into regs, K frags into regs
        bf16x8 va0 = *(const bf16x8*)&Vb[(size_t)kp2 * DK + db];
        bf16x8 va1 = *(const bf16x8*)&Vb[(size_t)(kp2 + 1) * DK + db];
        bf16x8 vb0 = *(const bf16x8*)&Vb[(size_t)(64 + kp2) * DK + db];
        bf16x8 vb1 = *(const bf16x8*)&Vb[(size_t)(64 + kp2 + 1) * DK + db];
        bf16x8 Kf[2][4][2];   // [tile parity][kt][c]
#pragma unroll
        for (int par = 0; par < 2; ++par)
#pragma unroll
            for (int kt = 0; kt < 4; ++kt)
#pragma unroll
                for (int c = 0; c < 2; ++c)
                    Kf[par][kt][c] = *(const bf16x8*)
                        &Kb[(size_t)(par * 64 + kt * 16 + l16) * DK +
                            c * 32 + quad * 8];

        float m_i[2] = { -1e30f, -1e30f };
        float l_i[2] = { 0.0f, 0.0f };     // LANE-PARTIAL; reduced in epilogue
        f32x4 o[2][4] = {};

        const int ktiles = 2 * bx + 2;     // always even
        for (int tt = 0; tt < ktiles; tt += 2) {
            const int bufA = (tt & 2);     // {0,2,0,2,...}
            const int bufB = bufA | 1;

            // ---- commit both prefetched V tiles ----
#pragma unroll
            for (int i = 0; i < 8; ++i) {
                short2v pa; pa.x = va0[i]; pa.y = va1[i];
                *(short2v*)&Vt[bufA][db + i][kp2] = pa;
                short2v pb; pb.x = vb0[i]; pb.y = vb1[i];
                *(short2v*)&Vt[bufB][db + i][kp2] = pb;
            }
            __syncthreads();               // one barrier per 2 tiles

            // ---- prefetch V tiles tt+2, tt+3 ----
            if (tt + 2 < ktiles) {
                const short* vp = &Vb[(size_t)((tt + 2) * 64 + kp2) * DK + db];
                va0 = *(const bf16x8*)vp;
                va1 = *(const bf16x8*)(vp + DK);
                vp += (size_t)64 * DK;
                vb0 = *(const bf16x8*)vp;
                vb1 = *(const bf16x8*)(vp + DK);
            }

            // ================= two tiles =================
#pragma unroll
            for (int sel = 0; sel < 2; ++sel) {
                const int t  = tt + sel;
                const int k0 = t * 64;
                const int buf = sel ? bufB : bufA;
                if (k0 > qlim) continue;   // wave has no live q rows here

                // ---- S^T = K * Q^T ----
                f32x4 sT2[2][4];
#pragma unroll
                for (int sub = 0; sub < 2; ++sub) {
#pragma unroll
                    for (int kt = 0; kt < 4; ++kt) sT2[sub][kt] = f32x4{};
#pragma unroll
                    for (int c = 0; c < 2; ++c)
#pragma unroll
                        for (int kt = 0; kt < 4; ++kt)
                            sT2[sub][kt] =
                                __builtin_amdgcn_mfma_f32_16x16x32_bf16(
                                    Kf[sel][kt][c], Qf[sub][c],
                                    sT2[sub][kt], 0, 0, 0);
                }

                // Kf[sel] dead now -> prefetch tile t+2 into it (WAR)
                if (k0 + 128 <= qlim) {
#pragma unroll
                    for (int kt = 0; kt < 4; ++kt)
#pragma unroll
                        for (int c = 0; c < 2; ++c)
                            Kf[sel][kt][c] = *(const bf16x8*)
                                &Kb[(size_t)(k0 + 128 + kt * 16 + l16) * DK +
                                    c * 32 + quad * 8];
                }

#pragma unroll
                for (int sub = 0; sub < 2; ++sub) {
                    f32x4* sT = sT2[sub];
                    const int qg = qbase + sub * 16 + l16;
                    if (k0 + 63 > qbase + sub * 16) {   // causal mask needed
#pragma unroll
                        for (int kt = 0; kt < 4; ++kt)
#pragma unroll
                            for (int r = 0; r < 4; ++r)
                                if (k0 + kt * 16 + quad * 4 + r > qg)
                                    sT[kt][r] = -1e30f;
                    }

                    // per-lane max (no cross-lane in common path)
                    float tmax = fmaxf(
                        fmaxf(fmaxf(sT[0][0], sT[0][1]),
                              fmaxf(sT[0][2], sT[0][3])),
                        fmaxf(fmaxf(fmaxf(sT[1][0], sT[1][1]),
                                    fmaxf(sT[1][2], sT[1][3])),
                              fmaxf(fmaxf(fmaxf(sT[2][0], sT[2][1]),
                                          fmaxf(sT[2][2], sT[2][3])),
                                    fmaxf(fmaxf(sT[3][0], sT[3][1]),
                                          fmaxf(sT[3][2], sT[3][3])))));
                    // defer-max: rescale only if some lane exceeds m+8
                    if (!__all(tmax <= m_i[sub] + 8.0f)) {
                        float tm = fmaxf(tmax, __shfl_xor(tmax, 16));
                        tm = fmaxf(tm, __shfl_xor(tm, 32));
                        float mnew = fmaxf(m_i[sub], tm);
                        float alpha = exp2f(m_i[sub] - mnew);
                        m_i[sub] = mnew;
                        l_i[sub] *= alpha;
#pragma unroll
                        for (int dt = 0; dt < 4; ++dt) {
                            o[sub][dt][0] *= alpha; o[sub][dt][1] *= alpha;
                            o[sub][dt][2] *= alpha; o[sub][dt][3] *= alpha;
                        }
                    }
                    const float mn = m_i[sub];
                    float rs = 0.0f;
                    const int prow = wave * 32 + sub * 16 + l16;
#pragma unroll
                    for (int kt = 0; kt < 4; ++kt) {
                        float p0 = exp2f(sT[kt][0] - mn);
                        float p1 = exp2f(sT[kt][1] - mn);
                        float p2 = exp2f(sT[kt][2] - mn);
                        float p3 = exp2f(sT[kt][3] - mn);
                        rs += (p0 + p1) + (p2 + p3);
                        uint2 uu;
                        uu.x = cvt_pk_bf16(p0, p1);
                        uu.y = cvt_pk_bf16(p2, p3);
                        *(uint2*)&Ps[prow][kt * 16 + quad * 4] = uu;
                    }
                    l_i[sub] += rs;        // lane-partial accumulate
                }

                // ---- O^T += V^T P^T ----
                bf16x8 Pf[2][2];
#pragma unroll
                for (int sub = 0; sub < 2; ++sub)
#pragma unroll
                    for (int c = 0; c < 2; ++c)
                        Pf[sub][c] = *(const bf16x8*)
                            &Ps[wave * 32 + sub * 16 + l16][c * 32 + quad * 8];
#pragma unroll
                for (int c = 0; c < 2; ++c)
#pragma unroll
                    for (int dt = 0; dt < 4; ++dt) {
                        bf16x8 av = *(const bf16x8*)
                            &Vt[buf][dt * 16 + l16][c * 32 + quad * 8];
#pragma unroll
                        for (int sub = 0; sub < 2; ++sub)
                            o[sub][dt] =
                                __builtin_amdgcn_mfma_f32_16x16x32_bf16(
                                    av, Pf[sub][c], o[sub][dt], 0, 0, 0);
                    }
            }
        }
        __syncthreads();   // protect Vt bufs before next half's first commit

        // ---- epilogue: reduce lane-partial l, normalize, write bf16 ----
#pragma unroll
        for (int sub = 0; sub < 2; ++sub) {
            float lt = l_i[sub];
            lt += __shfl_xor(lt, 16);
            lt += __shfl_xor(lt, 32);
            const float linv = 1.0f / lt;
            const int q = qbase + sub * 16 + l16;
            short* ob = &O[((size_t)bi * S_LEN + q) * D_MODEL + head * DK];
#pragma unroll
            for (int dt = 0; dt < 4; ++dt) {
                short4v h;
                h.x = f2bf(o[sub][dt][0] * linv);
                h.y = f2bf(o[sub][dt][1] * linv);
                h.z = f2bf(o[sub][dt][2] * linv);
                h.w = f2bf(o[sub][dt][3] * linv);
                *(short4v*)&ob[dt * 16 + quad * 4] = h;
            }
        }
    }
}

extern "C" void kernel_launch(void* const* d_in, const int* in_sizes, int n_in,
                              void* d_out, int out_size, void* d_ws, size_t ws_size,
                              hipStream_t stream) {
    const float* x  = (const float*)d_in[0];
    const float* Wq = (const float*)d_in[1];
    const float* Wk = (const float*)d_in[2];
    const float* Wv = (const float*)d_in[3];
    const float* Wo = (const float*)d_in[4];
    const int*   tp = (const int*)d_in[5];
    float* out = (float*)d_out;

    const int n  = BATCH * S_LEN * D_MODEL;       // 8388608
    const int nw = D_MODEL * D_MODEL;             // 1048576
    short* sw   = (short*)d_ws;
    short* xbf  = sw;
    short* Qbf  = sw + (size_t)n;
    short* Kbf  = sw + (size_t)2 * n;
    short* Vbf  = sw + (size_t)3 * n;
    short* Obf  = sw + (size_t)4 * n;
    short* Wqbf = sw + (size_t)5 * n;             // Wq;Wk;Wv contiguous (3072x1024)
    short* Wobf = Wqbf + (size_t)3 * nw;
    // RoPE table overlaid on Obf (dead until attn writes it; stream order
    // guarantees rope_tab -> proj_qkv(read) -> attn(overwrite) -> proj_out).
    float2* cst = (float2*)Obf;                   // 512 KB of the 16.8 MB region

    dim3 blk(256);
    conv_bf16<<<n / (256 * 8), blk, 0, stream>>>(x, xbf, n);
    dim3 gw(nw / (256 * 8), 4);
    conv_w4<<<gw, blk, 0, stream>>>(Wq, Wk, Wv, Wo, Wqbf);
    rope_tab<<<(S_LEN * 32) / 256, blk, 0, stream>>>(tp, cst);

    dim3 gqkv(3 * D_MODEL / 128, (BATCH * S_LEN) / 128);   // (24, 64)
    proj_qkv<<<gqkv, blk, 0, stream>>>(xbf, Wqbf, cst, Qbf, Kbf, Vbf);

    dim3 gattn(8, BATCH * NH);                             // paired causal
    attn_bf16<<<gattn, blk, 0, stream>>>(Qbf, Kbf, Vbf, Obf);

    dim3 gout(D_MODEL / 128, (BATCH * S_LEN) / 128);       // (8, 64)
    proj_out<<<gout, blk, 0, stream>>>(Obf, Wobf, out);
}